// Round 5
// baseline (101.337 us; speedup 1.0000x reference)
//
#include <hip/hip_runtime.h>
#include <math.h>

// Problem constants: N=8192, C=19, M=10, K=64 ; out[n, c, m] with cm = c*10+m
#define NN   8192
#define KK   64
#define CMV  190

// ---------- ws layout ----------
// [0 .. 4MB)      : float ab[NN][2*KK]  interleaved {a=1/(1+xv), b=-2x/(1+xv)}
// [4MB .. )       : float R[NN]         (sum_k x^2*a + ln(1+xv))

//======================================================================
// Kernel 1: prep — one wave per row (64 lanes == 64 k's), grid covers all rows
//======================================================================
__global__ __launch_bounds__(256)
void prep_kernel(const float* __restrict__ x, const float* __restrict__ xvar,
                 float* __restrict__ ab, float* __restrict__ R)
{
  const int gid  = blockIdx.x * 256 + threadIdx.x;   // element (n,k)
  const int n    = gid >> 6;
  const int lane = threadIdx.x & 63;

  float xv = x[gid];
  float v  = xvar[gid] + 1.0f;
  float a  = __builtin_amdgcn_rcpf(v);
  float b  = -2.0f * xv * a;
  ((float2*)ab)[gid] = make_float2(a, b);            // coalesced float2 store

  // r = x^2 * a + ln(v) ; logf builtin is log2 -> scale by ln2
  float r = fmaf(xv * xv, a, 0.69314718055994530942f * __builtin_amdgcn_logf(v));
#pragma unroll
  for (int s = 32; s; s >>= 1) r += __shfl_xor(r, s, 64);
  if (lane == 0) R[n] = r;
}

//======================================================================
// Kernel 2: main — thread = cm, TNF rows per block, NO LDS, NO barriers.
// Row data (ab, R) is wave-uniform -> scalar pipe; VALU does 2 fmac/element.
//======================================================================
#define TNF 8
#define ROWSTRIDE (2 * KK)

__global__ __launch_bounds__(192)
void main_kernel(const float* __restrict__ x, const float* __restrict__ xvar,
                 const float* __restrict__ proto, const float* __restrict__ pvar,
                 const float* __restrict__ ab, const float* __restrict__ R,
                 float* __restrict__ out)
{
  const int cm = threadIdx.x;
  const int n0 = blockIdx.x * TNF;
  if (cm >= CMV) return;

  // prototype row -> registers; also p^2 (saves one VALU op per element)
  float pc[KK], pc2[KK];
  {
    const float4* pp = (const float4*)(proto + (size_t)cm * KK);
#pragma unroll
    for (int q = 0; q < 16; ++q) {
      float4 t = pp[q];
      pc[4*q+0] = t.x; pc[4*q+1] = t.y; pc[4*q+2] = t.z; pc[4*q+3] = t.w;
    }
#pragma unroll
    for (int i = 0; i < KK; ++i) pc2[i] = pc[i] * pc[i];
  }

  // per-thread gate: outputs of this cm depend only on pvar[cm,:]
  bool ok = true;
  {
    const float4* pv4 = (const float4*)(pvar + (size_t)cm * KK);
#pragma unroll
    for (int q = 0; q < 16; ++q) {
      float4 t = pv4[q];
      ok = ok && (t.x == 1.0f) && (t.y == 1.0f) && (t.z == 1.0f) && (t.w == 1.0f);
    }
  }

  const float c1 = -0.5f / (float)KK;

  if (ok) {
    // FAST: sim_sum = sum_k ( pc2[k]*a[n,k] + pc[k]*b[n,k] ) + R[n]
#pragma unroll
    for (int n = 0; n < TNF; ++n) {
      const float* __restrict__ abr = ab + (size_t)(n0 + n) * ROWSTRIDE;
      float rn = R[n0 + n];                 // uniform -> s_load
      float acc0 = 0.f, acc1 = 0.f;         // two chains: hide fma latency
#pragma unroll
      for (int k = 0; k < KK; ++k) {
        acc0 = fmaf(pc2[k], abr[2*k+0], acc0);   // v_fmac, 1 SGPR src
        acc1 = fmaf(pc[k],  abr[2*k+1], acc1);   // v_fmac, 1 SGPR src
      }
      out[(size_t)(n0 + n) * CMV + cm] = c1 * (acc0 + acc1 + rn);
    }
  } else {
    // GENERAL fallback (not taken for this dataset; correctness path)
    for (int n = 0; n < TNF; ++n) {
      float s = 0.f;
      for (int k = 0; k < KK; ++k) {
        float xx = x[(size_t)(n0 + n) * KK + k];
        float vv = xvar[(size_t)(n0 + n) * KK + k] + pvar[(size_t)cm * KK + k];
        float d  = pc[k] - xx;
        s += d * d * __builtin_amdgcn_rcpf(vv)
           + 0.69314718055994530942f * __builtin_amdgcn_logf(vv);
      }
      out[(size_t)(n0 + n) * CMV + cm] = c1 * s;
    }
  }
}

//======================================================================
extern "C" void kernel_launch(void* const* d_in, const int* in_sizes, int n_in,
                              void* d_out, int out_size, void* d_ws, size_t ws_size,
                              hipStream_t stream) {
  const float* x     = (const float*)d_in[0];
  const float* xvar  = (const float*)d_in[1];
  const float* proto = (const float*)d_in[2];
  const float* pvar  = (const float*)d_in[3];
  float* out = (float*)d_out;

  char*  ws    = (char*)d_ws;
  float* ws_ab = (float*)ws;                              // 4 MB
  float* ws_R  = (float*)(ws + (size_t)NN * 2 * KK * 4);  // 32 KB

  prep_kernel<<<NN * KK / 256, 256, 0, stream>>>(x, xvar, ws_ab, ws_R);
  main_kernel<<<NN / TNF, 192, 0, stream>>>(x, xvar, proto, pvar, ws_ab, ws_R, out);
}

// Round 6
// 86.342 us; speedup vs baseline: 1.1737x; 1.1737x over previous
//
#include <hip/hip_runtime.h>
#include <math.h>

// Problem: N=8192, C=19, M=10, K=64 ; out[n, c, m], cm = c*10+m
#define NN   8192
#define KK   64
#define CMV  190
#define TNF  8

typedef _Float16 h2 __attribute__((ext_vector_type(2)));

#if defined(__has_builtin)
#  if __has_builtin(__builtin_amdgcn_fdot2)
#    define HAVE_FDOT2 1
#  endif
#endif

__device__ __forceinline__ float dot2acc(unsigned int wa, unsigned int rb, float acc) {
#ifdef HAVE_FDOT2
  return __builtin_amdgcn_fdot2(__builtin_bit_cast(h2, wa),
                                __builtin_bit_cast(h2, rb), acc, false);
#else
  h2 a = __builtin_bit_cast(h2, wa), b = __builtin_bit_cast(h2, rb);
  return fmaf((float)a.x, (float)b.x, fmaf((float)a.y, (float)b.y, acc));
#endif
}

// ---------- ws layout (bytes) ----------
// [0 .. 2MB)          : uint abpk[NN*KK]   {f16 a=1/(1+xv), f16 b=-2x/(1+xv)}
// [2MB .. )           : uint wpk[CMV*KK]   {f16 pc^2, f16 pc}
// [2MB+64KB .. )      : float R[NN]        sum_k x^2*a + ln(1+xv)
#define W_OFF  (NN * KK * 4)
#define R_OFF  (W_OFF + 65536)

//======================================================================
// Kernel 1: prep. blocks [0,2048): ab + R rows; blocks [2048,2096): W table.
//======================================================================
__global__ __launch_bounds__(256)
void prep_kernel(const float* __restrict__ x, const float* __restrict__ xvar,
                 const float* __restrict__ proto,
                 unsigned int* __restrict__ abpk, unsigned int* __restrict__ wpk,
                 float* __restrict__ R)
{
  const int b = blockIdx.x;
  if (b < NN * KK / 256) {
    const int gid  = b * 256 + threadIdx.x;     // element (n,k)
    const int n    = gid >> 6;
    const int lane = threadIdx.x & 63;
    float xv = x[gid];
    float v  = xvar[gid] + 1.0f;
    float a  = __builtin_amdgcn_rcpf(v);
    float bb = -2.0f * xv * a;
    h2 p; p.x = (_Float16)a; p.y = (_Float16)bb;
    abpk[gid] = __builtin_bit_cast(unsigned int, p);

    float r = fmaf(xv * xv, a, 0.69314718055994530942f * __builtin_amdgcn_logf(v));
#pragma unroll
    for (int s = 32; s; s >>= 1) r += __shfl_xor(r, s, 64);
    if (lane == 0) R[n] = r;
  } else {
    const int e = (b - NN * KK / 256) * 256 + threadIdx.x;
    if (e < CMV * KK) {
      float pc = proto[e];
      h2 p; p.x = (_Float16)(pc * pc); p.y = (_Float16)pc;
      wpk[e] = __builtin_bit_cast(unsigned int, p);
    }
  }
}

//======================================================================
// Kernel 2: main. thread = cm, TNF rows per block. No LDS, no barriers.
// Row stream: 16 x dwordx4 per row; 64 x v_dot2_f32_f16 per row.
//======================================================================
__global__ __launch_bounds__(192)
void main_kernel(const unsigned int* __restrict__ abpk,
                 const unsigned int* __restrict__ wpk,
                 const float* __restrict__ R,
                 const float* __restrict__ x, const float* __restrict__ xvar,
                 const float* __restrict__ proto, const float* __restrict__ pvar,
                 float* __restrict__ out)
{
  const int cm = threadIdx.x;
  const int n0 = blockIdx.x * TNF;
  if (cm >= CMV) return;

  // W row (packed {pc^2, pc}) -> 64 VGPRs
  uint4 w4[16];
  {
    const uint4* wp = (const uint4*)(wpk + cm * KK);
#pragma unroll
    for (int q = 0; q < 16; ++q) w4[q] = wp[q];
  }

  // per-thread gate: this cm's outputs depend only on pvar[cm,:]
  bool ok = true;
  {
    const float4* pv4 = (const float4*)(pvar + (size_t)cm * KK);
#pragma unroll
    for (int q = 0; q < 16; ++q) {
      float4 t = pv4[q];
      ok = ok && (t.x == 1.0f) && (t.y == 1.0f) && (t.z == 1.0f) && (t.w == 1.0f);
    }
  }

  const float c1 = -0.5f / (float)KK;

  if (ok) {
#pragma unroll 2
    for (int n = 0; n < TNF; ++n) {
      const uint4* rp = (const uint4*)(abpk + (size_t)(n0 + n) * KK);
      float acc0 = 0.f, acc1 = 0.f;
#pragma unroll
      for (int q = 0; q < 16; q += 2) {
        uint4 rv0 = rp[q], rv1 = rp[q + 1];
        acc0 = dot2acc(w4[q].x, rv0.x, acc0);
        acc0 = dot2acc(w4[q].y, rv0.y, acc0);
        acc0 = dot2acc(w4[q].z, rv0.z, acc0);
        acc0 = dot2acc(w4[q].w, rv0.w, acc0);
        acc1 = dot2acc(w4[q+1].x, rv1.x, acc1);
        acc1 = dot2acc(w4[q+1].y, rv1.y, acc1);
        acc1 = dot2acc(w4[q+1].z, rv1.z, acc1);
        acc1 = dot2acc(w4[q+1].w, rv1.w, acc1);
      }
      out[(size_t)(n0 + n) * CMV + cm] = c1 * (acc0 + acc1 + R[n0 + n]);
    }
  } else {
    // GENERAL fallback (unused for this dataset; correctness path)
    for (int n = 0; n < TNF; ++n) {
      float s = 0.f;
      for (int k = 0; k < KK; ++k) {
        float pc = proto[(size_t)cm * KK + k];
        float xx = x[(size_t)(n0 + n) * KK + k];
        float vv = xvar[(size_t)(n0 + n) * KK + k] + pvar[(size_t)cm * KK + k];
        float d  = pc - xx;
        s += d * d * __builtin_amdgcn_rcpf(vv)
           + 0.69314718055994530942f * __builtin_amdgcn_logf(vv);
      }
      out[(size_t)(n0 + n) * CMV + cm] = c1 * s;
    }
  }
}

//======================================================================
extern "C" void kernel_launch(void* const* d_in, const int* in_sizes, int n_in,
                              void* d_out, int out_size, void* d_ws, size_t ws_size,
                              hipStream_t stream) {
  const float* x     = (const float*)d_in[0];
  const float* xvar  = (const float*)d_in[1];
  const float* proto = (const float*)d_in[2];
  const float* pvar  = (const float*)d_in[3];
  float* out = (float*)d_out;

  char* ws = (char*)d_ws;
  unsigned int* ws_ab = (unsigned int*)ws;
  unsigned int* ws_w  = (unsigned int*)(ws + W_OFF);
  float*        ws_R  = (float*)(ws + R_OFF);

  const int prep_blocks = NN * KK / 256 + (CMV * KK + 255) / 256;  // 2048 + 48
  prep_kernel<<<prep_blocks, 256, 0, stream>>>(x, xvar, proto, ws_ab, ws_w, ws_R);
  main_kernel<<<NN / TNF, 192, 0, stream>>>(ws_ab, ws_w, ws_R,
                                            x, xvar, proto, pvar, out);
}

// Round 7
// 84.955 us; speedup vs baseline: 1.1928x; 1.0163x over previous
//
#include <hip/hip_runtime.h>
#include <math.h>

// Problem: N=8192, C=19, M=10, K=64 ; out[n, c, m], cm = c*10+m
// mls: out[n,cm] = -0.5/K * sum_k[ (p-x)^2/(xv+pv) + ln(xv+pv) ]
// With pv==1 (checked per-thread): = -0.5/K * ( sum_k pc^2*a + pc*b  +  R[n] )
//   a = 1/(1+xv), b = -2x*a, R[n] = sum_k x^2*a + ln(1+xv)
#define NN   8192
#define KK   64
#define CMV  190
#define TNF  8          // rows per block; block owns these rows exclusively
#define NTH  192        // 3 waves; thread t = cm (2 idle)

typedef _Float16 h2 __attribute__((ext_vector_type(2)));

#if defined(__has_builtin)
#  if __has_builtin(__builtin_amdgcn_fdot2)
#    define HAVE_FDOT2 1
#  endif
#endif

__device__ __forceinline__ float dot2acc(unsigned int wa, unsigned int rb, float acc) {
#ifdef HAVE_FDOT2
  return __builtin_amdgcn_fdot2(__builtin_bit_cast(h2, wa),
                                __builtin_bit_cast(h2, rb), acc, false);
#else
  h2 a = __builtin_bit_cast(h2, wa), b = __builtin_bit_cast(h2, rb);
  return fmaf((float)a.x, (float)b.x, fmaf((float)a.y, (float)b.y, acc));
#endif
}

//======================================================================
// Single fused kernel: in-block row prep (LDS) + f16-dot2 main. 1 dispatch,
// no workspace, one HBM pass over x/xvar/proto/pvar.
//======================================================================
__global__ __launch_bounds__(NTH)
void fused_kernel(const float* __restrict__ x, const float* __restrict__ xvar,
                  const float* __restrict__ proto, const float* __restrict__ pvar,
                  float* __restrict__ out)
{
  __shared__ unsigned int ab_lds[TNF * KK];  // {f16 a, f16 b} per (row,k)   2KB
  __shared__ float rtmp[TNF * KK];           // per-element r contributions  2KB
  __shared__ float R_lds[TNF];

  const int tid = threadIdx.x;
  const int n0  = blockIdx.x * TNF;
  const float ln2 = 0.69314718055994530942f;

  // ---- phase 1: this block's rows -> a,b packed + r contributions ----
  {
    const float* xb  = x    + (size_t)n0 * KK;   // 512 contiguous floats
    const float* xvb = xvar + (size_t)n0 * KK;
    for (int e = tid; e < TNF * KK; e += NTH) {
      float xv = xb[e];
      float v  = xvb[e] + 1.0f;
      float a  = __builtin_amdgcn_rcpf(v);
      float b  = -2.0f * xv * a;
      h2 p; p.x = (_Float16)a; p.y = (_Float16)b;
      ab_lds[e] = __builtin_bit_cast(unsigned int, p);
      rtmp[e]   = fmaf(xv * xv, a, ln2 * __builtin_amdgcn_logf(v));
    }
  }

  // ---- W row {pc^2, pc} f16-packed -> 16 uint4 regs; pvar gate (VMEM,
  //      overlaps with the barrier/reduce below) ----
  const int cm = tid;
  uint4 w4[16];
  bool ok = true;
  if (cm < CMV) {
    const float4* pp  = (const float4*)(proto + (size_t)cm * KK);
    const float4* pv4 = (const float4*)(pvar  + (size_t)cm * KK);
#pragma unroll
    for (int q = 0; q < 16; ++q) {
      float4 t = pp[q];
      h2 p0; p0.x = (_Float16)(t.x * t.x); p0.y = (_Float16)t.x;
      h2 p1; p1.x = (_Float16)(t.y * t.y); p1.y = (_Float16)t.y;
      h2 p2; p2.x = (_Float16)(t.z * t.z); p2.y = (_Float16)t.z;
      h2 p3; p3.x = (_Float16)(t.w * t.w); p3.y = (_Float16)t.w;
      w4[q].x = __builtin_bit_cast(unsigned int, p0);
      w4[q].y = __builtin_bit_cast(unsigned int, p1);
      w4[q].z = __builtin_bit_cast(unsigned int, p2);
      w4[q].w = __builtin_bit_cast(unsigned int, p3);
      float4 u = pv4[q];
      ok = ok && (u.x == 1.0f) && (u.y == 1.0f) && (u.z == 1.0f) && (u.w == 1.0f);
    }
  }

  __syncthreads();   // rtmp, ab_lds ready

  // ---- phase 2: wave 0 reduces rtmp -> R_lds[8] ----
  if (tid < 64) {
    const int r = tid >> 3, c = tid & 7;
    float s = 0.f;
#pragma unroll
    for (int j = 0; j < 8; ++j) s += rtmp[r * KK + c * 8 + j];
    s += __shfl_xor(s, 1, 64);
    s += __shfl_xor(s, 2, 64);
    s += __shfl_xor(s, 4, 64);
    if (c == 0) R_lds[r] = s;
  }
  __syncthreads();   // R_lds ready (last barrier)

  if (cm >= CMV) return;

  const float c1 = -0.5f / (float)KK;

  if (ok) {
#pragma unroll 2
    for (int n = 0; n < TNF; ++n) {
      const uint4* rp = (const uint4*)(ab_lds + n * KK);  // broadcast LDS reads
      float acc0 = 0.f, acc1 = 0.f;
#pragma unroll
      for (int q = 0; q < 16; q += 2) {
        uint4 rv0 = rp[q], rv1 = rp[q + 1];
        acc0 = dot2acc(w4[q].x,   rv0.x, acc0);
        acc0 = dot2acc(w4[q].y,   rv0.y, acc0);
        acc0 = dot2acc(w4[q].z,   rv0.z, acc0);
        acc0 = dot2acc(w4[q].w,   rv0.w, acc0);
        acc1 = dot2acc(w4[q+1].x, rv1.x, acc1);
        acc1 = dot2acc(w4[q+1].y, rv1.y, acc1);
        acc1 = dot2acc(w4[q+1].z, rv1.z, acc1);
        acc1 = dot2acc(w4[q+1].w, rv1.w, acc1);
      }
      out[(size_t)(n0 + n) * CMV + cm] = c1 * (acc0 + acc1 + R_lds[n]);
    }
  } else {
    // GENERAL fallback (unused for this dataset; exact-semantics path)
    for (int n = 0; n < TNF; ++n) {
      float s = 0.f;
      for (int k = 0; k < KK; ++k) {
        float pc = proto[(size_t)cm * KK + k];
        float xx = x[(size_t)(n0 + n) * KK + k];
        float vv = xvar[(size_t)(n0 + n) * KK + k] + pvar[(size_t)cm * KK + k];
        float d  = pc - xx;
        s += d * d * __builtin_amdgcn_rcpf(vv)
           + ln2 * __builtin_amdgcn_logf(vv);
      }
      out[(size_t)(n0 + n) * CMV + cm] = c1 * s;
    }
  }
}

//======================================================================
extern "C" void kernel_launch(void* const* d_in, const int* in_sizes, int n_in,
                              void* d_out, int out_size, void* d_ws, size_t ws_size,
                              hipStream_t stream) {
  const float* x     = (const float*)d_in[0];
  const float* xvar  = (const float*)d_in[1];
  const float* proto = (const float*)d_in[2];
  const float* pvar  = (const float*)d_in[3];
  float* out = (float*)d_out;

  fused_kernel<<<NN / TNF, NTH, 0, stream>>>(x, xvar, proto, pvar, out);
}